// Round 5
// baseline (231.591 us; speedup 1.0000x reference)
//
#include <hip/hip_runtime.h>
#include <hip/hip_bf16.h>
#include <math.h>

#define MEM_DIM 1024
#define N_CHILD 16384

#define BM 128          // n-rows per block
#define BN 64           // j-cols per block
// K handled in 32-elem fragments (kt = 0..31), 2-stage register pipeline

typedef __bf16 bf16_t;
typedef __bf16 bf16x8 __attribute__((ext_vector_type(8)));
typedef float f32x4 __attribute__((ext_vector_type(4)));

// Tiled fragment layout: matrix [R rows][1024 k] (bf16) stored as 1 KB chunks:
//   chunk(rb, kt) = rows [rb*16, rb*16+16) x k [kt*32, kt*32+32)
//   elem (r, k) -> dst[ (rb*32 + kt)*512 + q*128 + cl*8 + i ]
//   with cl = r%16, q = (k%32)/8, i = k%8.
// A wave's MFMA fragment load for chunk (rb,kt) is then base + lane*8 elems
// (lane = q*16+cl) -> one perfectly coalesced global_load_dwordx4 per fragment.

// ---------------- Kernel 0: fp32 -> bf16 tiled conversion (child_h + W_fh) ----------
// dst: [child_h tiled (N_CHILD*1024)] [W_fh tiled (1024*1024)] contiguous.
// Thread t writes dst chunk-slice [t*8, t*8+8) -> fully coalesced writes.
__global__ __launch_bounds__(256) void cvt_tile_kernel(const float* __restrict__ srcA,
                                                       int unitsA,   // N_CHILD/16*32
                                                       const float* __restrict__ srcB,
                                                       bf16_t* __restrict__ dst,
                                                       int unitsTot) {
    const int t = blockIdx.x * 256 + threadIdx.x;
    const int unit = t >> 6;                 // 512-elem unit = one (rb,kt) chunk
    if (unit >= unitsTot) return;
    const int w  = (t & 63) * 8;             // elem offset within unit
    const int q  = w >> 7;
    const int cl = (w >> 3) & 15;
    const float* src;
    int u;
    if (unit < unitsA) { src = srcA; u = unit; }
    else               { src = srcB; u = unit - unitsA; }
    const int rb = u >> 5;
    const int kt = u & 31;
    src += (size_t)(rb * 16 + cl) * MEM_DIM + kt * 32 + q * 8;
    float4 x = *(const float4*)src;
    float4 y = *(const float4*)(src + 4);
    bf16x8 o = { (bf16_t)x.x, (bf16_t)x.y, (bf16_t)x.z, (bf16_t)x.w,
                 (bf16_t)y.x, (bf16_t)y.y, (bf16_t)y.z, (bf16_t)y.w };
    *(bf16x8*)(dst + (size_t)t * 8) = o;
}

// ---------------- Kernel 1: i/u/o gate matvecs (fp32 exact) ----------------
__global__ void gates_kernel(const float* __restrict__ hsum,
                             const float* __restrict__ W_ih, const float* __restrict__ b_ih,
                             const float* __restrict__ W_uh, const float* __restrict__ b_uh,
                             const float* __restrict__ W_oh, const float* __restrict__ b_oh,
                             float* __restrict__ acc_c, float* __restrict__ o_ws) {
    const int j = blockIdx.x;
    const int tid = threadIdx.x;
    const float* wi = W_ih + (size_t)j * MEM_DIM;
    const float* wu = W_uh + (size_t)j * MEM_DIM;
    const float* wo = W_oh + (size_t)j * MEM_DIM;
    float si = 0.f, su = 0.f, so = 0.f;
    for (int k = tid; k < MEM_DIM; k += 256) {
        float hv = hsum[k];
        si += wi[k] * hv;
        su += wu[k] * hv;
        so += wo[k] * hv;
    }
    for (int off = 32; off > 0; off >>= 1) {
        si += __shfl_down(si, off, 64);
        su += __shfl_down(su, off, 64);
        so += __shfl_down(so, off, 64);
    }
    __shared__ float red[3][4];
    const int wave = tid >> 6, lane = tid & 63;
    if (lane == 0) { red[0][wave] = si; red[1][wave] = su; red[2][wave] = so; }
    __syncthreads();
    if (tid == 0) {
        float ti = red[0][0] + red[0][1] + red[0][2] + red[0][3] + b_ih[j];
        float tu = red[1][0] + red[1][1] + red[1][2] + red[1][3] + b_uh[j];
        float to = red[2][0] + red[2][1] + red[2][2] + red[2][3] + b_oh[j];
        float iv = 1.f / (1.f + expf(-ti));
        float uv = tanhf(tu);
        float ov = 1.f / (1.f + expf(-to));
        acc_c[j] = iv * uv;
        o_ws[j]  = ov;
    }
}

// ---------------- Kernel 2: fused f-gate GEMM, LDS-free K-loop ----------------
// Fragments loaded straight from the tiled bf16 buffers into registers
// (coalesced dwordx4), 2-stage software pipeline, NO barriers in the K-loop.
// Block tile 128n x 64j, 4 waves in 2x2, each wave 64n x 32j (32 acc regs).
__global__ __launch_bounds__(256, 4) void fused_gemm_bf16(
        const bf16_t* __restrict__ hbf, const bf16_t* __restrict__ wbf,
        const float* __restrict__ child_c, const float* __restrict__ b_fh,
        float* __restrict__ acc_c) {
    __shared__ float sred[BN];

    const int tid  = threadIdx.x;
    const int lane = tid & 63;
    const int wave = tid >> 6;
    const int wr = wave >> 1;        // n-half (64 rows)
    const int wc = wave & 1;         // j-half (32 cols)
    const int q  = lane >> 4;
    const int cl = lane & 15;

    // XCD-aware tile mapping: 2048 blocks, xcd = b&7; j sweeps fastest within
    // an XCD so 16 consecutive same-XCD blocks share one A-tile (L2-local).
    const int b   = blockIdx.x;
    const int xcd = b & 7;
    const int l   = b >> 3;          // 0..255
    const int jt  = l & 15;
    const int ntl = l >> 4;          // 0..15
    const int j0  = jt * BN;
    const int n0  = (xcd * 16 + ntl) * BM;

    // fragment pointers: chunk (rb, kt) at (rb*32 + kt)*512 + lane*8
    const int nb0 = (n0 >> 4) + wr * 4;   // A 16-row block base for this wave
    const int jb0 = (j0 >> 4) + wc * 2;   // B 16-col block base
    const bf16_t* pA[4];
    const bf16_t* pB[2];
#pragma unroll
    for (int mt = 0; mt < 4; mt++)
        pA[mt] = hbf + ((size_t)(nb0 + mt) * 32) * 512 + lane * 8;
#pragma unroll
    for (int nt = 0; nt < 2; nt++)
        pB[nt] = wbf + ((size_t)(jb0 + nt) * 32) * 512 + lane * 8;

    f32x4 acc[4][2];
#pragma unroll
    for (int a = 0; a < 4; a++)
#pragma unroll
        for (int c = 0; c < 2; c++) acc[a][c] = (f32x4)0.0f;

    bf16x8 af[2][4], bfr[2][2];

    auto loadStage = [&](int s) {
#pragma unroll
        for (int mt = 0; mt < 4; mt++) { af[s][mt] = *(const bf16x8*)pA[mt]; pA[mt] += 512; }
#pragma unroll
        for (int nt = 0; nt < 2; nt++) { bfr[s][nt] = *(const bf16x8*)pB[nt]; pB[nt] += 512; }
    };
    auto compute = [&](int s) {
#pragma unroll
        for (int mt = 0; mt < 4; mt++)
#pragma unroll
            for (int nt = 0; nt < 2; nt++)
                acc[mt][nt] = __builtin_amdgcn_mfma_f32_16x16x32_bf16(
                    af[s][mt], bfr[s][nt], acc[mt][nt], 0, 0, 0);
    };

    loadStage(0);                      // kt = 0
#pragma unroll 1
    for (int it = 0; it < 16; ++it) {  // 16 double-steps = 32 kt
        loadStage(1);                  // kt = 2*it+1
        compute(0);
        if (it < 15) loadStage(0);     // kt = 2*it+2
        compute(1);
    }

    // --- epilogue: f = sigmoid(S+b), colsum over 128 rows, atomic into acc_c ---
    if (tid < BN) sred[tid] = 0.0f;
    __syncthreads();

    float colsum[2] = {0.f, 0.f};
#pragma unroll
    for (int nt = 0; nt < 2; nt++) {
        const int col = j0 + wc * 32 + nt * 16 + cl;
        const float bias = b_fh[col];
#pragma unroll
        for (int mt = 0; mt < 4; mt++) {
#pragma unroll
            for (int r = 0; r < 4; r++) {
                const int row = n0 + wr * 64 + mt * 16 + q * 4 + r;  // C/D: col=lane&15, row=q*4+r
                float s = acc[mt][nt][r] + bias;
                float fg = 1.0f / (1.0f + __expf(-s));
                colsum[nt] += fg * child_c[(size_t)row * MEM_DIM + col];
            }
        }
        colsum[nt] += __shfl_xor(colsum[nt], 16, 64);
        colsum[nt] += __shfl_xor(colsum[nt], 32, 64);
    }
    if (q == 0) {
#pragma unroll
        for (int nt = 0; nt < 2; nt++)
            atomicAdd(&sred[wc * 32 + nt * 16 + cl], colsum[nt]);
    }
    __syncthreads();
    if (tid < BN) atomicAdd(&acc_c[j0 + tid], sred[tid]);
}

// ---------------- Fallback (ws too small): fp32-staging GEMM, 128x128 ----------------
#define LDS_STRIDE 40
__global__ __launch_bounds__(256) void fused_gemm_f32(
        const float* __restrict__ child_h, const float* __restrict__ child_c,
        const float* __restrict__ W_fh, const float* __restrict__ b_fh,
        float* __restrict__ acc_c) {
    __shared__ __align__(16) bf16_t sA[128 * LDS_STRIDE];
    __shared__ __align__(16) bf16_t sB[128 * LDS_STRIDE];
    __shared__ float sred[128];
    const int tid = threadIdx.x, lane = tid & 63, wave = tid >> 6;
    const int wr = wave >> 1, wc = wave & 1;
    const int j0 = blockIdx.x * 128, n0 = blockIdx.y * 128;
    const int q = lane >> 4, cl = lane & 15;
    typedef __bf16 bf16x4 __attribute__((ext_vector_type(4)));
    f32x4 acc[4][4];
#pragma unroll
    for (int a = 0; a < 4; a++)
#pragma unroll
        for (int c = 0; c < 4; c++) acc[a][c] = (f32x4)0.0f;
    for (int k0 = 0; k0 < MEM_DIM; k0 += 32) {
#pragma unroll
        for (int i = 0; i < 4; i++) {
            int f = tid + i * 256, row = f >> 3, col = (f & 7) * 4;
            float4 va = *(const float4*)(child_h + (size_t)(n0 + row) * MEM_DIM + k0 + col);
            float4 vb = *(const float4*)(W_fh    + (size_t)(j0 + row) * MEM_DIM + k0 + col);
            bf16x4 ba = { (bf16_t)va.x, (bf16_t)va.y, (bf16_t)va.z, (bf16_t)va.w };
            bf16x4 bb = { (bf16_t)vb.x, (bf16_t)vb.y, (bf16_t)vb.z, (bf16_t)vb.w };
            *(bf16x4*)(&sA[row * LDS_STRIDE + col]) = ba;
            *(bf16x4*)(&sB[row * LDS_STRIDE + col]) = bb;
        }
        __syncthreads();
        bf16x8 af[4], bfr[4];
#pragma unroll
        for (int mt = 0; mt < 4; mt++) {
            af[mt]  = *(const bf16x8*)(&sA[(wr * 64 + mt * 16 + cl) * LDS_STRIDE + q * 8]);
            bfr[mt] = *(const bf16x8*)(&sB[(wc * 64 + mt * 16 + cl) * LDS_STRIDE + q * 8]);
        }
#pragma unroll
        for (int mt = 0; mt < 4; mt++)
#pragma unroll
            for (int nt = 0; nt < 4; nt++)
                acc[mt][nt] = __builtin_amdgcn_mfma_f32_16x16x32_bf16(af[mt], bfr[nt], acc[mt][nt], 0, 0, 0);
        __syncthreads();
    }
    if (tid < 128) sred[tid] = 0.0f;
    __syncthreads();
    float colsum[4] = {0.f, 0.f, 0.f, 0.f};
#pragma unroll
    for (int nt = 0; nt < 4; nt++) {
        const int col = j0 + wc * 64 + nt * 16 + cl;
        const float bias = b_fh[col];
#pragma unroll
        for (int mt = 0; mt < 4; mt++)
#pragma unroll
            for (int r = 0; r < 4; r++) {
                const int row = n0 + wr * 64 + mt * 16 + q * 4 + r;
                float s = acc[mt][nt][r] + bias;
                float fg = 1.0f / (1.0f + __expf(-s));
                colsum[nt] += fg * child_c[(size_t)row * MEM_DIM + col];
            }
        colsum[nt] += __shfl_xor(colsum[nt], 16, 64);
        colsum[nt] += __shfl_xor(colsum[nt], 32, 64);
    }
    if (q == 0)
#pragma unroll
        for (int nt = 0; nt < 4; nt++)
            atomicAdd(&sred[wc * 64 + nt * 16 + cl], colsum[nt]);
    __syncthreads();
    if (tid < 128) atomicAdd(&acc_c[j0 + tid], sred[tid]);
}

// ---------------- Kernel 3: finalize c, h ----------------
__global__ void finalize_kernel(const float* __restrict__ acc_c,
                                const float* __restrict__ o_ws,
                                float* __restrict__ out) {
    int t = blockIdx.x * 256 + threadIdx.x;
    if (t < MEM_DIM) {
        float cv = acc_c[t];
        float hv = o_ws[t] * tanhf(cv);
        out[t] = cv;
        out[MEM_DIM + t] = hv;
    }
}

extern "C" void kernel_launch(void* const* d_in, const int* in_sizes, int n_in,
                              void* d_out, int out_size, void* d_ws, size_t ws_size,
                              hipStream_t stream) {
    const float* child_c = (const float*)d_in[0];
    const float* child_h = (const float*)d_in[1];
    const float* hsum    = (const float*)d_in[2];
    const float* W_ih    = (const float*)d_in[3];
    const float* b_ih    = (const float*)d_in[4];
    const float* W_fh    = (const float*)d_in[5];
    const float* b_fh    = (const float*)d_in[6];
    const float* W_uh    = (const float*)d_in[7];
    const float* b_uh    = (const float*)d_in[8];
    const float* W_oh    = (const float*)d_in[9];
    const float* b_oh    = (const float*)d_in[10];
    float* out   = (float*)d_out;

    float* acc_c = (float*)d_ws;              // 1024 f
    float* o_ws  = acc_c + MEM_DIM;           // 1024 f
    const size_t HBF_OFF = 8192;              // bytes
    const size_t HBF_BYTES = (size_t)N_CHILD * MEM_DIM * 2;   // 33.5 MB
    const size_t WBF_BYTES = (size_t)MEM_DIM * MEM_DIM * 2;   // 2 MB
    const size_t NEED = HBF_OFF + HBF_BYTES + WBF_BYTES;

    gates_kernel<<<MEM_DIM, 256, 0, stream>>>(hsum, W_ih, b_ih, W_uh, b_uh, W_oh, b_oh,
                                              acc_c, o_ws);

    if (ws_size >= NEED) {
        bf16_t* hbf = (bf16_t*)((char*)d_ws + HBF_OFF);
        bf16_t* wbf = hbf + (size_t)N_CHILD * MEM_DIM;
        const int unitsA  = (N_CHILD / 16) * 32;          // 32768 chunks
        const int unitsB  = (MEM_DIM / 16) * 32;          // 2048 chunks
        const int unitsT  = unitsA + unitsB;
        const int threads = unitsT * 64;                   // one thread per 8 elems
        cvt_tile_kernel<<<(threads + 255) / 256, 256, 0, stream>>>(
            child_h, unitsA, W_fh, hbf, unitsT);
        fused_gemm_bf16<<<(N_CHILD / BM) * (MEM_DIM / BN), 256, 0, stream>>>(
            hbf, wbf, child_c, b_fh, acc_c);
    } else {
        dim3 grid(MEM_DIM / 128, N_CHILD / 128);
        fused_gemm_f32<<<grid, 256, 0, stream>>>(child_h, child_c, W_fh, b_fh, acc_c);
    }
    finalize_kernel<<<(MEM_DIM + 255) / 256, 256, 0, stream>>>(acc_c, o_ws, out);
}